// Round 1
// baseline (44.271 us; speedup 1.0000x reference)
//
#include <hip/hip_runtime.h>
#include <math.h>

#define H 64
#define VOCAB 64
#define LSEQ 4096
#define NSLOTS 4
#define NP 3
#define EPS 1e-5f

__device__ __forceinline__ float wsum(float x) {
    #pragma unroll
    for (int m = 1; m < 64; m <<= 1) x += __shfl_xor(x, m);
    return x;
}
__device__ __forceinline__ float wmax(float x) {
    #pragma unroll
    for (int m = 1; m < 64; m <<= 1) x = fmaxf(x, __shfl_xor(x, m));
    return x;
}

// ws layout (floats):
//   enc_t   [64][64]        @ 0
//   score_t [64]            @ 4096
//   SkT     [3][64h][64v]   @ 4160   (transposed for coalesced logit reads)
//   Sv      [3][64v][64h]   @ 16448
// total 28736 floats = 112.25 KB

// Grid 384 = 6 segs x 64 tokens. Each block: encoder row for its token
// (redundant x6, ~300 FMA/thread), then one table row.
// seg 0..2 -> SkT pass seg (+ seg0 writes enc_t & score_t); seg 3..5 -> Sv.
__global__ __launch_bounds__(64) void build_tables(
    const float* __restrict__ embed,
    const float* __restrict__ ff1_w, const float* __restrict__ ff1_b,
    const float* __restrict__ ff2_w, const float* __restrict__ ff2_b,
    const float* __restrict__ enc_g, const float* __restrict__ enc_b,
    const float* __restrict__ g1_w,  const float* __restrict__ g1_b,
    const float* __restrict__ g2_w,  const float* __restrict__ g2_b,
    const float* __restrict__ rk_w,  const float* __restrict__ rk_b,
    const float* __restrict__ rv_w,  const float* __restrict__ rv_b,
    float* __restrict__ enc_t, float* __restrict__ score_t,
    float* __restrict__ SkT, float* __restrict__ Sv)
{
    const int seg  = blockIdx.x >> 6;
    const int v    = blockIdx.x & 63;
    const int lane = threadIdx.x;

    __shared__ float h_s[H];
    __shared__ float a1[2 * H];
    __shared__ float hid_s[H];

    h_s[lane] = embed[v * H + lane];
    __syncthreads();

    // FFN: 64 -> 128 (relu) -> 64
    float acc0 = ff1_b[lane], acc1 = ff1_b[lane + 64];
    #pragma unroll 8
    for (int d = 0; d < H; d++) {
        float hv = h_s[d];
        acc0 += hv * ff1_w[d * 128 + lane];
        acc1 += hv * ff1_w[d * 128 + lane + 64];
    }
    a1[lane]      = fmaxf(acc0, 0.f);
    a1[lane + 64] = fmaxf(acc1, 0.f);
    __syncthreads();

    float o = ff2_b[lane];
    #pragma unroll 8
    for (int j = 0; j < 2 * H; j++) o += a1[j] * ff2_w[j * H + lane];

    float x  = h_s[lane] + o;
    float mu = wsum(x) * (1.f / 64.f);
    float dv = x - mu;
    float var = wsum(dv * dv) * (1.f / 64.f);
    float hid = dv / sqrtf(var + EPS) * enc_g[lane] + enc_b[lane];
    hid_s[lane] = hid;
    __syncthreads();

    if (seg == 0) {
        enc_t[v * H + lane] = hid;
        // gate score: 64 -> 32 (relu) -> 1 -> sigmoid
        float p = 0.f;
        if (lane < 32) {
            float a = g1_b[lane];
            #pragma unroll 8
            for (int d = 0; d < H; d++) a += hid_s[d] * g1_w[d * 32 + lane];
            p = fmaxf(a, 0.f) * g2_w[lane];
        }
        p = wsum(p);
        if (lane == 0) score_t[v] = 1.f / (1.f + expf(-(p + g2_b[0])));
    }

    if (seg < 3) {
        const int p = seg;
        float acc = rk_b[p * H + lane];
        #pragma unroll 8
        for (int d = 0; d < H; d++) acc += hid_s[d] * rk_w[(p * H + d) * H + lane];
        SkT[(p * H + lane) * H + v] = acc;            // [p][h][v]
    } else {
        const int p = seg - 3;
        float acc = rv_b[p * H + lane];
        #pragma unroll 8
        for (int d = 0; d < H; d++) acc += hid_s[d] * rv_w[(p * H + d) * H + lane];
        Sv[(p * H + v) * H + lane] = acc;             // [p][v][h]
    }
}

// One block per batch, 256 threads = 4 waves; wave k owns slot k, lane = h/v.
__global__ __launch_bounds__(256) void per_batch(
    const int*   __restrict__ seq,
    const float* __restrict__ rq_w, const float* __restrict__ rq_b,
    const float* __restrict__ rn_g, const float* __restrict__ rn_b,
    const float* __restrict__ rd_q_w, const float* __restrict__ rd_q_b,
    const float* __restrict__ out_w, const float* __restrict__ out_b,
    const float* __restrict__ enc_t, const float* __restrict__ score_t,
    const float* __restrict__ SkT, const float* __restrict__ Sv,
    float* __restrict__ out)
{
    const int b    = blockIdx.x;
    const int tid  = threadIdx.x;
    const int wid  = tid >> 6;
    const int lane = tid & 63;
    const float scale = 0.125f; // 1/sqrt(H)

    __shared__ int   seq_s[LSEQ];
    __shared__ int   cnt_s[VOCAB];
    __shared__ float sc_s[VOCAB];
    __shared__ float sl[NSLOTS][H];
    __shared__ float sq[NSLOTS][H];
    __shared__ float wl[NSLOTS][H];
    __shared__ unsigned long long red[4];
    __shared__ int   chosen_pos[NSLOTS], chosen_tok[NSLOTS];
    __shared__ float l4[NSLOTS];
    __shared__ float rbuf[H];

    const int* sb = seq + (size_t)b * LSEQ;
    #pragma unroll
    for (int i = 0; i < LSEQ / 256; i++) seq_s[i * 256 + tid] = sb[i * 256 + tid];
    if (tid < VOCAB) { cnt_s[tid] = 0; sc_s[tid] = score_t[tid]; }
    __syncthreads();

    #pragma unroll
    for (int i = 0; i < LSEQ / 256; i++) atomicAdd(&cnt_s[seq_s[i * 256 + tid]], 1);
    __syncthreads();

    // exact lax.top_k(4) emulation: key = (score_bits<<32) | (~pos)
    for (int r = 0; r < NSLOTS; r++) {
        unsigned long long best = 0ull;
        for (int i = 0; i < LSEQ / 256; i++) {
            int pos = i * 256 + tid;
            bool skip = false;
            for (int q = 0; q < r; q++) skip |= (pos == chosen_pos[q]);
            if (skip) continue;
            unsigned sbits = __float_as_uint(sc_s[seq_s[pos]]);
            unsigned long long key =
                ((unsigned long long)sbits << 32) | (unsigned long long)(0xFFFFFFFFu - (unsigned)pos);
            best = key > best ? key : best;
        }
        #pragma unroll
        for (int m = 1; m < 64; m <<= 1) {
            unsigned long long o = __shfl_xor(best, m);
            best = o > best ? o : best;
        }
        if (lane == 0) red[wid] = best;
        __syncthreads();
        if (tid == 0) {
            unsigned long long bb = red[0];
            for (int wI = 1; wI < 4; wI++) bb = red[wI] > bb ? red[wI] : bb;
            int pos = (int)(0xFFFFFFFFu - (unsigned)(bb & 0xFFFFFFFFu));
            chosen_pos[r] = pos;
            chosen_tok[r] = seq_s[pos];
        }
        __syncthreads();
    }

    // slot pipeline: wave wid owns slot wid
    const int tok = chosen_tok[wid];
    float s = enc_t[tok * H + lane];
    sl[wid][lane] = s;
    const float cnt_f = (float)cnt_s[lane];

    for (int p = 0; p < NP; p++) {
        // Sq = slot @ rq_w[p] + rq_b[p]
        float acc = rq_b[p * H + lane];
        #pragma unroll 8
        for (int d = 0; d < H; d++) acc += sl[wid][d] * rq_w[(p * H + d) * H + lane];
        sq[wid][lane] = acc;

        // logits over vocab (lane = v), via transposed Sk table (coalesced)
        float lg = 0.f;
        const float* skp = SkT + p * H * H;
        #pragma unroll 8
        for (int hh = 0; hh < H; hh++) lg += sq[wid][hh] * skp[hh * H + lane];
        lg *= scale;

        float key = cnt_f > 0.f ? lg : -1e30f;
        float mx  = wmax(key);
        float w   = cnt_f * expf(lg - mx);   // cnt==0 -> w==0 exactly
        float denom = wsum(w);
        wl[wid][lane] = w;

        // attn @ Sv, lane = h
        float ao = 0.f;
        const float* svp = Sv + p * H * H;
        #pragma unroll 8
        for (int vv = 0; vv < H; vv++) ao += wl[wid][vv] * svp[vv * H + lane];

        float x  = s + ao / denom;
        float mu = wsum(x) * (1.f / 64.f);
        float dv = x - mu;
        float var = wsum(dv * dv) * (1.f / 64.f);
        s = dv / sqrtf(var + EPS) * rn_g[p * H + lane] + rn_b[p * H + lane];
        sl[wid][lane] = s;
    }

    // read head: q from last token (all waves compute redundantly)
    const int last = seq_s[LSEQ - 1];
    float q = rd_q_b[lane];
    #pragma unroll 8
    for (int d = 0; d < H; d++) q += enc_t[last * H + d] * rd_q_w[d * H + lane];
    float lk = wsum(s * q) * scale;
    if (lane == 0) l4[wid] = lk;
    __syncthreads();

    if (wid == 0) {
        float l0 = l4[0], l1 = l4[1], l2 = l4[2], l3 = l4[3];
        float mx = fmaxf(fmaxf(l0, l1), fmaxf(l2, l3));
        float e0 = expf(l0 - mx), e1 = expf(l1 - mx), e2 = expf(l2 - mx), e3 = expf(l3 - mx);
        float dn = e0 + e1 + e2 + e3;
        rbuf[lane] = (e0 * sl[0][lane] + e1 * sl[1][lane] + e2 * sl[2][lane] + e3 * sl[3][lane]) / dn;
    }
    __syncthreads();

    if (wid == 0) {
        float o = out_b[lane];
        #pragma unroll 8
        for (int hh = 0; hh < H; hh++) o += rbuf[hh] * out_w[hh * VOCAB + lane];
        out[(size_t)b * VOCAB + lane] = o;
    }
}

extern "C" void kernel_launch(void* const* d_in, const int* in_sizes, int n_in,
                              void* d_out, int out_size, void* d_ws, size_t ws_size,
                              hipStream_t stream) {
    const int*   seq    = (const int*)  d_in[0];
    const float* embed  = (const float*)d_in[1];
    const float* ff1_w  = (const float*)d_in[2];
    const float* ff1_b  = (const float*)d_in[3];
    const float* ff2_w  = (const float*)d_in[4];
    const float* ff2_b  = (const float*)d_in[5];
    const float* enc_g  = (const float*)d_in[6];
    const float* enc_b  = (const float*)d_in[7];
    const float* g1_w   = (const float*)d_in[8];
    const float* g1_b   = (const float*)d_in[9];
    const float* g2_w   = (const float*)d_in[10];
    const float* g2_b   = (const float*)d_in[11];
    const float* rq_w   = (const float*)d_in[12];
    const float* rq_b   = (const float*)d_in[13];
    const float* rk_w   = (const float*)d_in[14];
    const float* rk_b   = (const float*)d_in[15];
    const float* rv_w   = (const float*)d_in[16];
    const float* rv_b   = (const float*)d_in[17];
    const float* rn_g   = (const float*)d_in[18];
    const float* rn_b   = (const float*)d_in[19];
    const float* rd_q_w = (const float*)d_in[20];
    const float* rd_q_b = (const float*)d_in[21];
    const float* out_w  = (const float*)d_in[22];
    const float* out_b  = (const float*)d_in[23];
    float* out = (float*)d_out;

    const int B = in_sizes[0] / LSEQ;

    float* ws      = (float*)d_ws;
    float* enc_t   = ws;                // 4096
    float* score_t = ws + 4096;         // 64
    float* SkT     = ws + 4160;         // 12288
    float* Sv      = ws + 16448;        // 12288

    build_tables<<<384, 64, 0, stream>>>(
        embed, ff1_w, ff1_b, ff2_w, ff2_b, enc_g, enc_b,
        g1_w, g1_b, g2_w, g2_b, rk_w, rk_b, rv_w, rv_b,
        enc_t, score_t, SkT, Sv);

    per_batch<<<B, 256, 0, stream>>>(
        seq, rq_w, rq_b, rn_g, rn_b, rd_q_w, rd_q_b, out_w, out_b,
        enc_t, score_t, SkT, Sv, out);
}

// Round 2
// 32.727 us; speedup vs baseline: 1.3528x; 1.3528x over previous
//
#include <hip/hip_runtime.h>
#include <math.h>

#define H 64
#define VOCAB 64
#define LSEQ 4096
#define NSLOTS 4
#define NP 3
#define EPS 1e-5f

typedef unsigned long long ull;

__device__ __forceinline__ float wsum(float x) {
    #pragma unroll
    for (int m = 1; m < 64; m <<= 1) x += __shfl_xor(x, m);
    return x;
}
__device__ __forceinline__ float wmax(float x) {
    #pragma unroll
    for (int m = 1; m < 64; m <<= 1) x = fmaxf(x, __shfl_xor(x, m));
    return x;
}
__device__ __forceinline__ ull wmax64(ull x) {
    #pragma unroll
    for (int m = 1; m < 64; m <<= 1) {
        ull o = __shfl_xor(x, m);
        x = o > x ? o : x;
    }
    return x;
}
__device__ __forceinline__ int wsumi(int x) {
    #pragma unroll
    for (int m = 1; m < 64; m <<= 1) x += __shfl_xor(x, m);
    return x;
}

// ws layout (floats):
//   enc_t   [64][64]          @ 0
//   score_t [64]              @ 4096
//   SkT     [3][64h][64v]     @ 4160
//   Sv      [3][64v][64h]     @ 16448
//   M       [3][64i][64v]     @ 28736   (rq_w @ Sk^T, fused)
//   c       [3][64v]          @ 41024   (rq_b . Sk)
//   q_t     [64][64]          @ 41216   (per-token read-head query)

// ---- kernel 1a: per-token encoder tables (unchanged structure) ----
__global__ __launch_bounds__(64) void build_tables(
    const float* __restrict__ embed,
    const float* __restrict__ ff1_w, const float* __restrict__ ff1_b,
    const float* __restrict__ ff2_w, const float* __restrict__ ff2_b,
    const float* __restrict__ enc_g, const float* __restrict__ enc_b,
    const float* __restrict__ g1_w,  const float* __restrict__ g1_b,
    const float* __restrict__ g2_w,  const float* __restrict__ g2_b,
    const float* __restrict__ rk_w,  const float* __restrict__ rk_b,
    const float* __restrict__ rv_w,  const float* __restrict__ rv_b,
    float* __restrict__ enc_t, float* __restrict__ score_t,
    float* __restrict__ SkT, float* __restrict__ Sv)
{
    const int seg  = blockIdx.x >> 6;
    const int v    = blockIdx.x & 63;
    const int lane = threadIdx.x;

    __shared__ float h_s[H];
    __shared__ float a1[2 * H];
    __shared__ float hid_s[H];

    h_s[lane] = embed[v * H + lane];
    __syncthreads();

    float acc0 = ff1_b[lane], acc1 = ff1_b[lane + 64];
    #pragma unroll 8
    for (int d = 0; d < H; d++) {
        float hv = h_s[d];
        acc0 += hv * ff1_w[d * 128 + lane];
        acc1 += hv * ff1_w[d * 128 + lane + 64];
    }
    a1[lane]      = fmaxf(acc0, 0.f);
    a1[lane + 64] = fmaxf(acc1, 0.f);
    __syncthreads();

    float o = ff2_b[lane];
    #pragma unroll 8
    for (int j = 0; j < 2 * H; j++) o += a1[j] * ff2_w[j * H + lane];

    float x  = h_s[lane] + o;
    float mu = wsum(x) * (1.f / 64.f);
    float dv = x - mu;
    float var = wsum(dv * dv) * (1.f / 64.f);
    float hid = dv / sqrtf(var + EPS) * enc_g[lane] + enc_b[lane];
    hid_s[lane] = hid;
    __syncthreads();

    if (seg == 0) {
        enc_t[v * H + lane] = hid;
        float p = 0.f;
        if (lane < 32) {
            float a = g1_b[lane];
            #pragma unroll 8
            for (int d = 0; d < H; d++) a += hid_s[d] * g1_w[d * 32 + lane];
            p = fmaxf(a, 0.f) * g2_w[lane];
        }
        p = wsum(p);
        if (lane == 0) score_t[v] = 1.f / (1.f + expf(-(p + g2_b[0])));
    }

    if (seg < 3) {
        const int p = seg;
        float acc = rk_b[p * H + lane];
        #pragma unroll 8
        for (int d = 0; d < H; d++) acc += hid_s[d] * rk_w[(p * H + d) * H + lane];
        SkT[(p * H + lane) * H + v] = acc;
    } else {
        const int p = seg - 3;
        float acc = rv_b[p * H + lane];
        #pragma unroll 8
        for (int d = 0; d < H; d++) acc += hid_s[d] * rv_w[(p * H + d) * H + lane];
        Sv[(p * H + v) * H + lane] = acc;
    }
}

// ---- kernel 1b: fused query projection M = rq_w @ Sk^T, c = rq_b . Sk, q_table ----
__global__ __launch_bounds__(64) void build_tables2(
    const float* __restrict__ rq_w, const float* __restrict__ rq_b,
    const float* __restrict__ rd_q_w, const float* __restrict__ rd_q_b,
    const float* __restrict__ enc_t, const float* __restrict__ SkT,
    float* __restrict__ M, float* __restrict__ c, float* __restrict__ q_t)
{
    const int blk = blockIdx.x, lane = threadIdx.x;
    if (blk < NP * 64) {
        const int p = blk >> 6, i = blk & 63;
        const float* sk = SkT + p * 4096;
        float acc = 0.f;
        #pragma unroll 8
        for (int d = 0; d < 64; d++) acc += rq_w[(p * 64 + i) * 64 + d] * sk[d * 64 + lane];
        M[p * 4096 + i * 64 + lane] = acc;
        if (i == 0) {
            float cv = 0.f;
            #pragma unroll 8
            for (int d = 0; d < 64; d++) cv += rq_b[p * 64 + d] * sk[d * 64 + lane];
            c[p * 64 + lane] = cv;
        }
    } else {
        const int v = blk - NP * 64;
        float acc = rd_q_b[lane];
        #pragma unroll 8
        for (int d = 0; d < 64; d++) acc += enc_t[v * 64 + d] * rd_q_w[d * 64 + lane];
        q_t[v * 64 + lane] = acc;
    }
}

// ---- kernel 2: per-batch histogram + selection + 3-pass pipeline (tables in LDS) ----
__global__ __launch_bounds__(512) void per_batch2(
    const int*   __restrict__ seq,
    const float* __restrict__ score_t, const float* __restrict__ enc_t,
    const float* __restrict__ Sv_g, const float* __restrict__ M_g,
    const float* __restrict__ c_g, const float* __restrict__ q_t,
    const float* __restrict__ rn_g, const float* __restrict__ rn_b,
    const float* __restrict__ out_w, const float* __restrict__ out_b,
    float* __restrict__ out)
{
    __shared__ float Ms[NP * 4096];      // 48 KB
    __shared__ float Svs[NP * 4096];     // 48 KB
    __shared__ float ows[4096];          // 16 KB
    __shared__ float cs[NP * 64];
    __shared__ float rngs[NP * 64], rnbs[NP * 64];
    __shared__ float scs[64], obs[64];
    __shared__ int   whist[8][64];
    __shared__ int   fps[64];
    __shared__ int   cnts[64];
    __shared__ int   chosen[NSLOTS];
    __shared__ int   last_s;
    __shared__ float slN[NSLOTS][64];
    __shared__ float l4[NSLOTS];

    const int b = blockIdx.x, tid = threadIdx.x;
    const int wid = tid >> 6, lane = tid & 63;

    // seq: 2 x int4 per thread
    const int4* s4 = (const int4*)(seq + (size_t)b * LSEQ);
    int4 v0 = s4[tid];
    int4 v1 = s4[tid + 512];
    if (tid == 511) last_s = v1.w;

    // stage tables global -> LDS (float4)
    {
        const float4* a = (const float4*)M_g; float4* d = (float4*)Ms;
        #pragma unroll
        for (int i = 0; i < 6; i++) d[tid + i * 512] = a[tid + i * 512];
    }
    {
        const float4* a = (const float4*)Sv_g; float4* d = (float4*)Svs;
        #pragma unroll
        for (int i = 0; i < 6; i++) d[tid + i * 512] = a[tid + i * 512];
    }
    {
        const float4* a = (const float4*)out_w; float4* d = (float4*)ows;
        #pragma unroll
        for (int i = 0; i < 2; i++) d[tid + i * 512] = a[tid + i * 512];
    }
    if (tid < NP * 64) { cs[tid] = c_g[tid]; rngs[tid] = rn_g[tid]; rnbs[tid] = rn_b[tid]; }
    if (tid < 64) { scs[tid] = score_t[tid]; obs[tid] = out_b[tid]; fps[tid] = 0x7FFFFFFF; }
    whist[wid][lane] = 0;
    __syncthreads();

    // histogram + first-position (per-wave private counts)
    {
        int p0 = tid * 4, p1 = (tid + 512) * 4;
        int t;
        t = v0.x; atomicAdd(&whist[wid][t], 1); atomicMin(&fps[t], p0 + 0);
        t = v0.y; atomicAdd(&whist[wid][t], 1); atomicMin(&fps[t], p0 + 1);
        t = v0.z; atomicAdd(&whist[wid][t], 1); atomicMin(&fps[t], p0 + 2);
        t = v0.w; atomicAdd(&whist[wid][t], 1); atomicMin(&fps[t], p0 + 3);
        t = v1.x; atomicAdd(&whist[wid][t], 1); atomicMin(&fps[t], p1 + 0);
        t = v1.y; atomicAdd(&whist[wid][t], 1); atomicMin(&fps[t], p1 + 1);
        t = v1.z; atomicAdd(&whist[wid][t], 1); atomicMin(&fps[t], p1 + 2);
        t = v1.w; atomicAdd(&whist[wid][t], 1); atomicMin(&fps[t], p1 + 3);
    }
    __syncthreads();
    if (tid < 64) {
        int csum = 0;
        #pragma unroll
        for (int w = 0; w < 8; w++) csum += whist[w][tid];
        cnts[tid] = csum;
    }
    __syncthreads();

    // slot multiset selection on wave 0: sort by (score desc, first_pos asc), fill by counts
    if (wid == 0) {
        int cnt = cnts[lane];
        ull key = cnt > 0
            ? (((ull)__float_as_uint(scs[lane]) << 32) | (ull)(0xFFFFFFFFu - (unsigned)fps[lane]))
            : 0ull;
        int filled = 0;
        #pragma unroll
        for (int r = 0; r < NSLOTS; r++) {
            ull k = (filled >= NSLOTS) ? 0ull : key;
            ull m = wmax64(k);
            int tl = (m != 0ull && k == m) ? min(cnt, NSLOTS - filled) : 0;
            if (tl > 0) {
                for (int j = 0; j < tl; j++) chosen[filled + j] = lane;
                key = 0ull;
            }
            filled += wsumi(tl);
        }
    }
    __syncthreads();

    const float cntf = (float)cnts[lane];

    // pipeline: wave wid owns slot wid; all operands in LDS/regs
    if (wid < NSLOTS) {
        const int tok = chosen[wid];
        float s = enc_t[tok * 64 + lane];
        #pragma unroll
        for (int p = 0; p < NP; p++) {
            // logits over vocab (lane = v): slot . M[:,v] + c[v]
            float lg = cs[p * 64 + lane];
            const float* Mp = Ms + p * 4096;
            #pragma unroll
            for (int i = 0; i < 64; i++) lg += __shfl(s, i) * Mp[i * 64 + lane];
            lg *= 0.125f;

            float kk = cntf > 0.f ? lg : -1e30f;
            float mx = wmax(kk);
            float w = cntf * expf(lg - mx);      // cnt==0 -> exactly 0
            float denom = wsum(w);

            // attn @ Sv (lane = h)
            float ao = 0.f;
            const float* Svp = Svs + p * 4096;
            #pragma unroll
            for (int v = 0; v < 64; v++) ao += __shfl(w, v) * Svp[v * 64 + lane];

            float x  = s + ao / denom;
            float mu = wsum(x) * (1.f / 64.f);
            float dv = x - mu;
            float var = wsum(dv * dv) * (1.f / 64.f);
            s = dv / sqrtf(var + EPS) * rngs[p * 64 + lane] + rnbs[p * 64 + lane];
        }
        // read head logit
        float q = q_t[last_s * 64 + lane];
        float lk = wsum(s * q) * 0.125f;
        if (lane == 0) l4[wid] = lk;
        slN[wid][lane] = s;
    }
    __syncthreads();

    if (wid == 0) {
        float l0 = l4[0], l1 = l4[1], l2 = l4[2], l3 = l4[3];
        float mx = fmaxf(fmaxf(l0, l1), fmaxf(l2, l3));
        float e0 = expf(l0 - mx), e1 = expf(l1 - mx), e2 = expf(l2 - mx), e3 = expf(l3 - mx);
        float dn = e0 + e1 + e2 + e3;
        float r = (e0 * slN[0][lane] + e1 * slN[1][lane] + e2 * slN[2][lane] + e3 * slN[3][lane]) / dn;

        float o = obs[lane];
        #pragma unroll
        for (int hh = 0; hh < 64; hh++) o += __shfl(r, hh) * ows[hh * 64 + lane];
        out[(size_t)b * VOCAB + lane] = o;
    }
}

extern "C" void kernel_launch(void* const* d_in, const int* in_sizes, int n_in,
                              void* d_out, int out_size, void* d_ws, size_t ws_size,
                              hipStream_t stream) {
    const int*   seq    = (const int*)  d_in[0];
    const float* embed  = (const float*)d_in[1];
    const float* ff1_w  = (const float*)d_in[2];
    const float* ff1_b  = (const float*)d_in[3];
    const float* ff2_w  = (const float*)d_in[4];
    const float* ff2_b  = (const float*)d_in[5];
    const float* enc_g  = (const float*)d_in[6];
    const float* enc_b  = (const float*)d_in[7];
    const float* g1_w   = (const float*)d_in[8];
    const float* g1_b   = (const float*)d_in[9];
    const float* g2_w   = (const float*)d_in[10];
    const float* g2_b   = (const float*)d_in[11];
    const float* rq_w   = (const float*)d_in[12];
    const float* rq_b   = (const float*)d_in[13];
    const float* rk_w   = (const float*)d_in[14];
    const float* rk_b   = (const float*)d_in[15];
    const float* rv_w   = (const float*)d_in[16];
    const float* rv_b   = (const float*)d_in[17];
    const float* rn_g   = (const float*)d_in[18];
    const float* rn_b   = (const float*)d_in[19];
    const float* rd_q_w = (const float*)d_in[20];
    const float* rd_q_b = (const float*)d_in[21];
    const float* out_w  = (const float*)d_in[22];
    const float* out_b  = (const float*)d_in[23];
    float* out = (float*)d_out;

    const int B = in_sizes[0] / LSEQ;

    float* ws      = (float*)d_ws;
    float* enc_t   = ws;                // 4096
    float* score_t = ws + 4096;         // 64
    float* SkT     = ws + 4160;         // 12288
    float* Sv      = ws + 16448;        // 12288
    float* M       = ws + 28736;        // 12288
    float* c       = ws + 41024;        // 192
    float* q_t     = ws + 41216;        // 4096

    build_tables<<<384, 64, 0, stream>>>(
        embed, ff1_w, ff1_b, ff2_w, ff2_b, enc_g, enc_b,
        g1_w, g1_b, g2_w, g2_b, rk_w, rk_b, rv_w, rv_b,
        enc_t, score_t, SkT, Sv);

    build_tables2<<<NP * 64 + 64, 64, 0, stream>>>(
        rq_w, rq_b, rd_q_w, rd_q_b, enc_t, SkT, M, c, q_t);

    per_batch2<<<B, 512, 0, stream>>>(
        seq, score_t, enc_t, Sv, M, c, q_t, rn_g, rn_b, out_w, out_b, out);
}

// Round 3
// 30.406 us; speedup vs baseline: 1.4560x; 1.0763x over previous
//
#include <hip/hip_runtime.h>
#include <math.h>

#define H 64
#define VOCAB 64
#define LSEQ 4096
#define NSLOTS 4
#define NP 3
#define EPS 1e-5f

typedef unsigned long long ull;

__device__ __forceinline__ float wsum(float x) {
    #pragma unroll
    for (int m = 1; m < 64; m <<= 1) x += __shfl_xor(x, m);
    return x;
}
__device__ __forceinline__ float wmax(float x) {
    #pragma unroll
    for (int m = 1; m < 64; m <<= 1) x = fmaxf(x, __shfl_xor(x, m));
    return x;
}
__device__ __forceinline__ ull wmax64(ull x) {
    #pragma unroll
    for (int m = 1; m < 64; m <<= 1) {
        ull o = __shfl_xor(x, m);
        x = o > x ? o : x;
    }
    return x;
}
__device__ __forceinline__ int wsumi(int x) {
    #pragma unroll
    for (int m = 1; m < 64; m <<= 1) x += __shfl_xor(x, m);
    return x;
}

// ws layout (floats):
//   enc_t   [64][64]          @ 0
//   score_t [64]              @ 4096
//   SkT     [3][64h][64v]     @ 4160
//   Sv      [3][64v][64h]     @ 16448
//   M       [3][64i][64v]     @ 28736   (rq_w @ Sk^T, fused)
//   c       [3][64v]          @ 41024   (rq_b . Sk)
//   q_t     [64][64]          @ 41216   (per-token read-head query)

// ---- kernel 1a: per-token encoder tables ----
__global__ __launch_bounds__(64) void build_tables(
    const float* __restrict__ embed,
    const float* __restrict__ ff1_w, const float* __restrict__ ff1_b,
    const float* __restrict__ ff2_w, const float* __restrict__ ff2_b,
    const float* __restrict__ enc_g, const float* __restrict__ enc_b,
    const float* __restrict__ g1_w,  const float* __restrict__ g1_b,
    const float* __restrict__ g2_w,  const float* __restrict__ g2_b,
    const float* __restrict__ rk_w,  const float* __restrict__ rk_b,
    const float* __restrict__ rv_w,  const float* __restrict__ rv_b,
    float* __restrict__ enc_t, float* __restrict__ score_t,
    float* __restrict__ SkT, float* __restrict__ Sv)
{
    const int seg  = blockIdx.x >> 6;
    const int v    = blockIdx.x & 63;
    const int lane = threadIdx.x;

    __shared__ float h_s[H];
    __shared__ float a1[2 * H];
    __shared__ float hid_s[H];

    h_s[lane] = embed[v * H + lane];
    __syncthreads();

    float acc0 = ff1_b[lane], acc1 = ff1_b[lane + 64];
    #pragma unroll 8
    for (int d = 0; d < H; d++) {
        float hv = h_s[d];
        acc0 += hv * ff1_w[d * 128 + lane];
        acc1 += hv * ff1_w[d * 128 + lane + 64];
    }
    a1[lane]      = fmaxf(acc0, 0.f);
    a1[lane + 64] = fmaxf(acc1, 0.f);
    __syncthreads();

    float o = ff2_b[lane];
    #pragma unroll 8
    for (int j = 0; j < 2 * H; j++) o += a1[j] * ff2_w[j * H + lane];

    float x  = h_s[lane] + o;
    float mu = wsum(x) * (1.f / 64.f);
    float dv = x - mu;
    float var = wsum(dv * dv) * (1.f / 64.f);
    float hid = dv / sqrtf(var + EPS) * enc_g[lane] + enc_b[lane];
    hid_s[lane] = hid;
    __syncthreads();

    if (seg == 0) {
        enc_t[v * H + lane] = hid;
        float p = 0.f;
        if (lane < 32) {
            float a = g1_b[lane];
            #pragma unroll 8
            for (int d = 0; d < H; d++) a += hid_s[d] * g1_w[d * 32 + lane];
            p = fmaxf(a, 0.f) * g2_w[lane];
        }
        p = wsum(p);
        if (lane == 0) score_t[v] = 1.f / (1.f + expf(-(p + g2_b[0])));
    }

    if (seg < 3) {
        const int p = seg;
        float acc = rk_b[p * H + lane];
        #pragma unroll 8
        for (int d = 0; d < H; d++) acc += hid_s[d] * rk_w[(p * H + d) * H + lane];
        SkT[(p * H + lane) * H + v] = acc;
    } else {
        const int p = seg - 3;
        float acc = rv_b[p * H + lane];
        #pragma unroll 8
        for (int d = 0; d < H; d++) acc += hid_s[d] * rv_w[(p * H + d) * H + lane];
        Sv[(p * H + v) * H + lane] = acc;
    }
}

// ---- kernel 1b: fused query projection M = rq_w @ Sk^T, c = rq_b . Sk, q_table ----
__global__ __launch_bounds__(64) void build_tables2(
    const float* __restrict__ rq_w, const float* __restrict__ rq_b,
    const float* __restrict__ rd_q_w, const float* __restrict__ rd_q_b,
    const float* __restrict__ enc_t, const float* __restrict__ SkT,
    float* __restrict__ M, float* __restrict__ c, float* __restrict__ q_t)
{
    const int blk = blockIdx.x, lane = threadIdx.x;
    if (blk < NP * 64) {
        const int p = blk >> 6, i = blk & 63;
        const float* sk = SkT + p * 4096;
        float acc = 0.f;
        #pragma unroll 8
        for (int d = 0; d < 64; d++) acc += rq_w[(p * 64 + i) * 64 + d] * sk[d * 64 + lane];
        M[p * 4096 + i * 64 + lane] = acc;
        if (i == 0) {
            float cv = 0.f;
            #pragma unroll 8
            for (int d = 0; d < 64; d++) cv += rq_b[p * 64 + d] * sk[d * 64 + lane];
            c[p * 64 + lane] = cv;
        }
    } else {
        const int v = blk - NP * 64;
        float acc = rd_q_b[lane];
        #pragma unroll 8
        for (int d = 0; d < 64; d++) acc += enc_t[v * 64 + d] * rd_q_w[d * 64 + lane];
        q_t[v * 64 + lane] = acc;
    }
}

// ---- kernel 2: per-batch histogram + selection + 3-pass pipeline ----
// No table staging: M/Sv/out_w read direct from global (L2/L3-resident),
// fully-unrolled 4-accumulator matvecs.
__global__ __launch_bounds__(512) void per_batch3(
    const int*   __restrict__ seq,
    const float* __restrict__ score_t, const float* __restrict__ enc_t,
    const float* __restrict__ Sv_g, const float* __restrict__ M_g,
    const float* __restrict__ c_g, const float* __restrict__ q_t,
    const float* __restrict__ rn_g, const float* __restrict__ rn_b,
    const float* __restrict__ out_w, const float* __restrict__ out_b,
    float* __restrict__ out)
{
    __shared__ int   whist[8][64];
    __shared__ int   wfps[8][64];
    __shared__ int   cnts[64];
    __shared__ int   fps[64];
    __shared__ float scs[64];
    __shared__ int   chosen[NSLOTS];
    __shared__ int   last_s;
    __shared__ float slN[NSLOTS][64];
    __shared__ float l4[NSLOTS];

    const int b = blockIdx.x, tid = threadIdx.x;
    const int wid = tid >> 6, lane = tid & 63;

    const int4* s4 = (const int4*)(seq + (size_t)b * LSEQ);
    int4 v0 = s4[tid];
    int4 v1 = s4[tid + 512];
    if (tid == 511) last_s = v1.w;
    whist[wid][lane] = 0;
    wfps[wid][lane]  = 0x7FFFFFFF;
    if (tid < 64) scs[tid] = score_t[tid];
    __syncthreads();

    {
        int p0 = tid * 4, p1 = (tid + 512) * 4;
        int* hw = whist[wid];
        int* fw = wfps[wid];
        atomicAdd(&hw[v0.x], 1); atomicMin(&fw[v0.x], p0 + 0);
        atomicAdd(&hw[v0.y], 1); atomicMin(&fw[v0.y], p0 + 1);
        atomicAdd(&hw[v0.z], 1); atomicMin(&fw[v0.z], p0 + 2);
        atomicAdd(&hw[v0.w], 1); atomicMin(&fw[v0.w], p0 + 3);
        atomicAdd(&hw[v1.x], 1); atomicMin(&fw[v1.x], p1 + 0);
        atomicAdd(&hw[v1.y], 1); atomicMin(&fw[v1.y], p1 + 1);
        atomicAdd(&hw[v1.z], 1); atomicMin(&fw[v1.z], p1 + 2);
        atomicAdd(&hw[v1.w], 1); atomicMin(&fw[v1.w], p1 + 3);
    }
    __syncthreads();
    if (tid < 64) {
        int cs_ = 0, fp_ = 0x7FFFFFFF;
        #pragma unroll
        for (int w = 0; w < 8; w++) { cs_ += whist[w][tid]; fp_ = min(fp_, wfps[w][tid]); }
        cnts[tid] = cs_; fps[tid] = fp_;
    }
    __syncthreads();

    // prefetch pass-0 M column into regs (addresses independent of selection)
    float mreg[64];
    if (wid < NSLOTS) {
        #pragma unroll
        for (int i = 0; i < 64; i++) mreg[i] = M_g[i * 64 + lane];
    }

    // slot multiset selection on wave 0: (score desc, first_pos asc), fill by counts
    if (wid == 0) {
        int cnt = cnts[lane];
        ull key = cnt > 0
            ? (((ull)__float_as_uint(scs[lane]) << 32) | (ull)(0xFFFFFFFFu - (unsigned)fps[lane]))
            : 0ull;
        int filled = 0;
        #pragma unroll
        for (int r = 0; r < NSLOTS; r++) {
            ull k = (filled >= NSLOTS) ? 0ull : key;
            ull m = wmax64(k);
            int tl = (m != 0ull && k == m) ? min(cnt, NSLOTS - filled) : 0;
            if (tl > 0) {
                for (int j = 0; j < tl; j++) chosen[filled + j] = lane;
                key = 0ull;
            }
            filled += wsumi(tl);
        }
    }
    __syncthreads();

    if (wid < NSLOTS) {
        const int tok = chosen[wid];
        float s = enc_t[tok * 64 + lane];
        float q = q_t[last_s * 64 + lane];
        const float cntf = (float)cnts[lane];

        #pragma unroll
        for (int p = 0; p < NP; p++) {
            float c0 = c_g[p * 64 + lane];
            float rg = rn_g[p * 64 + lane];
            float rb = rn_b[p * 64 + lane];

            float a0 = 0.f, a1 = 0.f, a2 = 0.f, a3 = 0.f;
            if (p == 0) {
                #pragma unroll
                for (int i = 0; i < 64; i += 4) {
                    a0 += __shfl(s, i + 0) * mreg[i + 0];
                    a1 += __shfl(s, i + 1) * mreg[i + 1];
                    a2 += __shfl(s, i + 2) * mreg[i + 2];
                    a3 += __shfl(s, i + 3) * mreg[i + 3];
                }
            } else {
                const float* Mp = M_g + p * 4096;
                #pragma unroll
                for (int i = 0; i < 64; i += 4) {
                    a0 += __shfl(s, i + 0) * Mp[(i + 0) * 64 + lane];
                    a1 += __shfl(s, i + 1) * Mp[(i + 1) * 64 + lane];
                    a2 += __shfl(s, i + 2) * Mp[(i + 2) * 64 + lane];
                    a3 += __shfl(s, i + 3) * Mp[(i + 3) * 64 + lane];
                }
            }
            float lg = (c0 + ((a0 + a1) + (a2 + a3))) * 0.125f;

            float kk = cntf > 0.f ? lg : -1e30f;
            float mx = wmax(kk);
            float w  = cntf * __expf(lg - mx);   // cnt==0 -> exactly 0
            float denom = wsum(w);

            float b0 = 0.f, b1 = 0.f, b2 = 0.f, b3 = 0.f;
            const float* Svp = Sv_g + p * 4096;
            #pragma unroll
            for (int v = 0; v < 64; v += 4) {
                b0 += __shfl(w, v + 0) * Svp[(v + 0) * 64 + lane];
                b1 += __shfl(w, v + 1) * Svp[(v + 1) * 64 + lane];
                b2 += __shfl(w, v + 2) * Svp[(v + 2) * 64 + lane];
                b3 += __shfl(w, v + 3) * Svp[(v + 3) * 64 + lane];
            }
            float ao = ((b0 + b1) + (b2 + b3)) / denom;

            float x  = s + ao;
            float mu = wsum(x) * (1.f / 64.f);
            float dv = x - mu;
            float var = wsum(dv * dv) * (1.f / 64.f);
            s = dv * rsqrtf(var + EPS) * rg + rb;
        }
        float lk = wsum(s * q) * 0.125f;
        if (lane == 0) l4[wid] = lk;
        slN[wid][lane] = s;
    }
    __syncthreads();

    if (wid == 0) {
        float l0 = l4[0], l1 = l4[1], l2 = l4[2], l3 = l4[3];
        float mx = fmaxf(fmaxf(l0, l1), fmaxf(l2, l3));
        float e0 = __expf(l0 - mx), e1 = __expf(l1 - mx);
        float e2 = __expf(l2 - mx), e3 = __expf(l3 - mx);
        float dn = e0 + e1 + e2 + e3;
        float r = (e0 * slN[0][lane] + e1 * slN[1][lane] + e2 * slN[2][lane] + e3 * slN[3][lane]) / dn;

        float o0 = out_b[lane], o1 = 0.f, o2 = 0.f, o3 = 0.f;
        #pragma unroll
        for (int hh = 0; hh < 64; hh += 4) {
            o0 += __shfl(r, hh + 0) * out_w[(hh + 0) * 64 + lane];
            o1 += __shfl(r, hh + 1) * out_w[(hh + 1) * 64 + lane];
            o2 += __shfl(r, hh + 2) * out_w[(hh + 2) * 64 + lane];
            o3 += __shfl(r, hh + 3) * out_w[(hh + 3) * 64 + lane];
        }
        out[(size_t)b * VOCAB + lane] = ((o0 + o1) + (o2 + o3));
    }
}

extern "C" void kernel_launch(void* const* d_in, const int* in_sizes, int n_in,
                              void* d_out, int out_size, void* d_ws, size_t ws_size,
                              hipStream_t stream) {
    const int*   seq    = (const int*)  d_in[0];
    const float* embed  = (const float*)d_in[1];
    const float* ff1_w  = (const float*)d_in[2];
    const float* ff1_b  = (const float*)d_in[3];
    const float* ff2_w  = (const float*)d_in[4];
    const float* ff2_b  = (const float*)d_in[5];
    const float* enc_g  = (const float*)d_in[6];
    const float* enc_b  = (const float*)d_in[7];
    const float* g1_w   = (const float*)d_in[8];
    const float* g1_b   = (const float*)d_in[9];
    const float* g2_w   = (const float*)d_in[10];
    const float* g2_b   = (const float*)d_in[11];
    const float* rq_w   = (const float*)d_in[12];
    const float* rq_b   = (const float*)d_in[13];
    const float* rk_w   = (const float*)d_in[14];
    const float* rk_b   = (const float*)d_in[15];
    const float* rv_w   = (const float*)d_in[16];
    const float* rv_b   = (const float*)d_in[17];
    const float* rn_g   = (const float*)d_in[18];
    const float* rn_b   = (const float*)d_in[19];
    const float* rd_q_w = (const float*)d_in[20];
    const float* rd_q_b = (const float*)d_in[21];
    const float* out_w  = (const float*)d_in[22];
    const float* out_b  = (const float*)d_in[23];
    float* out = (float*)d_out;

    const int B = in_sizes[0] / LSEQ;

    float* ws      = (float*)d_ws;
    float* enc_t   = ws;                // 4096
    float* score_t = ws + 4096;         // 64
    float* SkT     = ws + 4160;         // 12288
    float* Sv      = ws + 16448;        // 12288
    float* M       = ws + 28736;        // 12288
    float* c       = ws + 41024;        // 192
    float* q_t     = ws + 41216;        // 4096

    build_tables<<<384, 64, 0, stream>>>(
        embed, ff1_w, ff1_b, ff2_w, ff2_b, enc_g, enc_b,
        g1_w, g1_b, g2_w, g2_b, rk_w, rk_b, rv_w, rv_b,
        enc_t, score_t, SkT, Sv);

    build_tables2<<<NP * 64 + 64, 64, 0, stream>>>(
        rq_w, rq_b, rd_q_w, rd_q_b, enc_t, SkT, M, c, q_t);

    per_batch3<<<B, 512, 0, stream>>>(
        seq, score_t, enc_t, Sv, M, c, q_t, rn_g, rn_b, out_w, out_b, out);
}

// Round 4
// 29.948 us; speedup vs baseline: 1.4782x; 1.0153x over previous
//
#include <hip/hip_runtime.h>
#include <math.h>

#define H 64
#define VOCAB 64
#define LSEQ 4096
#define NSLOTS 4
#define NP 3
#define EPS 1e-5f

typedef unsigned long long ull;

__device__ __forceinline__ float wsum(float x) {
    #pragma unroll
    for (int m = 1; m < 64; m <<= 1) x += __shfl_xor(x, m);
    return x;
}
__device__ __forceinline__ ull wmax64(ull x) {
    #pragma unroll
    for (int m = 1; m < 64; m <<= 1) {
        ull o = __shfl_xor(x, m);
        x = o > x ? o : x;
    }
    return x;
}
__device__ __forceinline__ int wsumi(int x) {
    #pragma unroll
    for (int m = 1; m < 64; m <<= 1) x += __shfl_xor(x, m);
    return x;
}

// ws layout (floats):
//   enc_t  [64][64]        @ 0      per-token encoder output
//   score  [64]            @ 4096   gate score per token
//   c_t    [3][64v]        @ 4160   rq_b . Sk[v]
//   q_t    [64][64]        @ 4352   read-head query per last-token
//   MT     [3][64v][64d]   @ 8448   (rq_w @ Sk^T)^T : logits_v = s . MT[v][:] + c[v]
//   SvT    [3][64h][64v]   @ 20736  Sv transposed: ao_h = w . SvT[h][:]
//   owT    [64v][64h]      @ 33024  out_w transposed
// total 37120 floats = 145 KB

// ---- kernel 1: ALL tables in one launch. 384 blocks = 6 segs x 64 tokens.
// seg 0..2 (p=seg): Sk row v -> MT column + c   (seg0 also enc_t, score, q_t)
// seg 3..5 (p=seg-3): Sv row v -> SvT scatter   (seg3 also owT row)
__global__ __launch_bounds__(64) void build_all(
    const float* __restrict__ embed,
    const float* __restrict__ ff1_w, const float* __restrict__ ff1_b,
    const float* __restrict__ ff2_w, const float* __restrict__ ff2_b,
    const float* __restrict__ enc_g, const float* __restrict__ enc_b,
    const float* __restrict__ g1_w,  const float* __restrict__ g1_b,
    const float* __restrict__ g2_w,  const float* __restrict__ g2_b,
    const float* __restrict__ rq_w,  const float* __restrict__ rq_b,
    const float* __restrict__ rk_w,  const float* __restrict__ rk_b,
    const float* __restrict__ rv_w,  const float* __restrict__ rv_b,
    const float* __restrict__ rd_q_w, const float* __restrict__ rd_q_b,
    const float* __restrict__ out_w,
    float* __restrict__ enc_t, float* __restrict__ score_t,
    float* __restrict__ c_t, float* __restrict__ q_t,
    float* __restrict__ MT, float* __restrict__ SvT, float* __restrict__ owT)
{
    const int seg  = blockIdx.x >> 6;
    const int v    = blockIdx.x & 63;
    const int lane = threadIdx.x;

    __shared__ float h_s[H];
    __shared__ float a1[2 * H];
    __shared__ float hid_s[H];
    __shared__ float sk_s[H];

    h_s[lane] = embed[v * H + lane];
    __syncthreads();

    // FFN 64 -> 128 (relu), 4-way ILP
    float pA[4] = {0, 0, 0, 0}, pB[4] = {0, 0, 0, 0};
    #pragma unroll
    for (int c4 = 0; c4 < 4; c4++)
        #pragma unroll
        for (int d = 0; d < 16; d++) {
            int dd = c4 * 16 + d;
            float hv = h_s[dd];
            pA[c4] += hv * ff1_w[dd * 128 + lane];
            pB[c4] += hv * ff1_w[dd * 128 + lane + 64];
        }
    a1[lane]      = fmaxf(ff1_b[lane]      + ((pA[0] + pA[1]) + (pA[2] + pA[3])), 0.f);
    a1[lane + 64] = fmaxf(ff1_b[lane + 64] + ((pB[0] + pB[1]) + (pB[2] + pB[3])), 0.f);
    __syncthreads();

    // FFN 128 -> 64, 4-way ILP
    float pO[4] = {0, 0, 0, 0};
    #pragma unroll
    for (int c4 = 0; c4 < 4; c4++)
        #pragma unroll
        for (int j = 0; j < 32; j++) {
            int jj = c4 * 32 + j;
            pO[c4] += a1[jj] * ff2_w[jj * H + lane];
        }
    float o = ff2_b[lane] + ((pO[0] + pO[1]) + (pO[2] + pO[3]));

    // LayerNorm (interleaved sum / sumsq)
    float x = h_s[lane] + o;
    float s1 = x, s2 = x * x;
    #pragma unroll
    for (int m = 1; m < 64; m <<= 1) { s1 += __shfl_xor(s1, m); s2 += __shfl_xor(s2, m); }
    float mu  = s1 * (1.f / 64.f);
    float var = s2 * (1.f / 64.f) - mu * mu;
    float hid = (x - mu) * rsqrtf(var + EPS) * enc_g[lane] + enc_b[lane];
    hid_s[lane] = hid;
    __syncthreads();

    if (seg == 0) {
        enc_t[v * H + lane] = hid;
        // gate score
        float p = 0.f;
        if (lane < 32) {
            float a[2] = {0, 0};
            #pragma unroll
            for (int c2 = 0; c2 < 2; c2++)
                #pragma unroll
                for (int d = 0; d < 32; d++) {
                    int dd = c2 * 32 + d;
                    a[c2] += hid_s[dd] * g1_w[dd * 32 + lane];
                }
            p = fmaxf(g1_b[lane] + a[0] + a[1], 0.f) * g2_w[lane];
        }
        p = wsum(p);
        if (lane == 0) score_t[v] = 1.f / (1.f + expf(-(p + g2_b[0])));
        // read-head query table row
        float qa[4] = {0, 0, 0, 0};
        #pragma unroll
        for (int c4 = 0; c4 < 4; c4++)
            #pragma unroll
            for (int d = 0; d < 16; d++) {
                int dd = c4 * 16 + d;
                qa[c4] += hid_s[dd] * rd_q_w[dd * H + lane];
            }
        q_t[v * H + lane] = rd_q_b[lane] + ((qa[0] + qa[1]) + (qa[2] + qa[3]));
    }

    if (seg < 3) {
        const int p = seg;
        // Sk row v
        float ka[4] = {0, 0, 0, 0};
        #pragma unroll
        for (int c4 = 0; c4 < 4; c4++)
            #pragma unroll
            for (int d = 0; d < 16; d++) {
                int dd = c4 * 16 + d;
                ka[c4] += hid_s[dd] * rk_w[(p * H + dd) * H + lane];
            }
        float skv = rk_b[p * H + lane] + ((ka[0] + ka[1]) + (ka[2] + ka[3]));
        sk_s[lane] = skv;
        // c[p][v] = rq_b . Sk[v]
        float cpart = wsum(rq_b[p * H + lane] * skv);
        if (lane == 0) c_t[p * 64 + v] = cpart;
        __syncthreads();
        // MT[p][v][d] = rq_w[p][d][:] . Sk[v][:]   (lane = d, coalesced write)
        const float4* rw4 = (const float4*)(rq_w + (size_t)(p * 64 + lane) * 64);
        const float4* sk4 = (const float4*)sk_s;
        float ma[4] = {0, 0, 0, 0};
        #pragma unroll
        for (int i = 0; i < 16; i++) {
            float4 w4 = rw4[i];
            float4 s4 = sk4[i];
            ma[0] += w4.x * s4.x; ma[1] += w4.y * s4.y;
            ma[2] += w4.z * s4.z; ma[3] += w4.w * s4.w;
        }
        MT[p * 4096 + v * 64 + lane] = ((ma[0] + ma[1]) + (ma[2] + ma[3]));
    } else {
        const int p = seg - 3;
        float va[4] = {0, 0, 0, 0};
        #pragma unroll
        for (int c4 = 0; c4 < 4; c4++)
            #pragma unroll
            for (int d = 0; d < 16; d++) {
                int dd = c4 * 16 + d;
                va[c4] += hid_s[dd] * rv_w[(p * H + dd) * H + lane];
            }
        float svv = rv_b[p * H + lane] + ((va[0] + va[1]) + (va[2] + va[3]));
        SvT[p * 4096 + lane * 64 + v] = svv;           // scatter: SvT[h][v]
        if (seg == 3) owT[v * 64 + lane] = out_w[lane * 64 + v];
    }
}

// ---- kernel 2: per-batch histogram + selection + pipeline ----
__global__ __launch_bounds__(256) void run_batches(
    const int*   __restrict__ seq,
    const float* __restrict__ score_t, const float* __restrict__ enc_t,
    const float* __restrict__ c_t, const float* __restrict__ q_t,
    const float* __restrict__ MT, const float* __restrict__ SvT,
    const float* __restrict__ owT,
    const float* __restrict__ rn_g, const float* __restrict__ rn_b,
    const float* __restrict__ out_b,
    float* __restrict__ out)
{
    __shared__ int   whist[4][64];
    __shared__ int   wfps[4][64];
    __shared__ int   cnts[64];
    __shared__ int   fps[64];
    __shared__ int   chosen[NSLOTS];
    __shared__ int   last_s;
    __shared__ float sls[NSLOTS][64];
    __shared__ float wls[NSLOTS][64];
    __shared__ float slN[NSLOTS][64];
    __shared__ float l4[NSLOTS];
    __shared__ float rbuf[64];

    const int b = blockIdx.x, tid = threadIdx.x;
    const int wid = tid >> 6, lane = tid & 63;

    const int4* s4 = (const int4*)(seq + (size_t)b * LSEQ);
    int4 t0 = s4[tid];
    int4 t1 = s4[tid + 256];
    int4 t2 = s4[tid + 512];
    int4 t3 = s4[tid + 768];
    if (tid == 255) last_s = t3.w;
    whist[wid][lane] = 0;
    wfps[wid][lane]  = 0x7FFFFFFF;
    __syncthreads();

    {
        int* hw = whist[wid];
        int* fw = wfps[wid];
        int p0 = tid * 4, p1 = p0 + 1024, p2 = p0 + 2048, p3 = p0 + 3072;
        atomicAdd(&hw[t0.x], 1); atomicMin(&fw[t0.x], p0 + 0);
        atomicAdd(&hw[t0.y], 1); atomicMin(&fw[t0.y], p0 + 1);
        atomicAdd(&hw[t0.z], 1); atomicMin(&fw[t0.z], p0 + 2);
        atomicAdd(&hw[t0.w], 1); atomicMin(&fw[t0.w], p0 + 3);
        atomicAdd(&hw[t1.x], 1); atomicMin(&fw[t1.x], p1 + 0);
        atomicAdd(&hw[t1.y], 1); atomicMin(&fw[t1.y], p1 + 1);
        atomicAdd(&hw[t1.z], 1); atomicMin(&fw[t1.z], p1 + 2);
        atomicAdd(&hw[t1.w], 1); atomicMin(&fw[t1.w], p1 + 3);
        atomicAdd(&hw[t2.x], 1); atomicMin(&fw[t2.x], p2 + 0);
        atomicAdd(&hw[t2.y], 1); atomicMin(&fw[t2.y], p2 + 1);
        atomicAdd(&hw[t2.z], 1); atomicMin(&fw[t2.z], p2 + 2);
        atomicAdd(&hw[t2.w], 1); atomicMin(&fw[t2.w], p2 + 3);
        atomicAdd(&hw[t3.x], 1); atomicMin(&fw[t3.x], p3 + 0);
        atomicAdd(&hw[t3.y], 1); atomicMin(&fw[t3.y], p3 + 1);
        atomicAdd(&hw[t3.z], 1); atomicMin(&fw[t3.z], p3 + 2);
        atomicAdd(&hw[t3.w], 1); atomicMin(&fw[t3.w], p3 + 3);
    }
    __syncthreads();
    if (tid < 64) {
        int cs_ = whist[0][tid] + whist[1][tid] + whist[2][tid] + whist[3][tid];
        int fp_ = min(min(wfps[0][tid], wfps[1][tid]), min(wfps[2][tid], wfps[3][tid]));
        cnts[tid] = cs_; fps[tid] = fp_;
    }
    __syncthreads();

    // selection on wave 0: (score desc, first-pos asc), fill by counts; early exit
    if (wid == 0) {
        int cnt = cnts[lane];
        float sc = score_t[lane];
        ull key = cnt > 0
            ? (((ull)__float_as_uint(sc) << 32) | (ull)(0xFFFFFFFFu - (unsigned)fps[lane]))
            : 0ull;
        int filled = 0;
        for (int r = 0; r < NSLOTS && filled < NSLOTS; r++) {
            ull m = wmax64(key);
            bool win = (key == m) && (m != 0ull);
            int tl = win ? min(cnt, NSLOTS - filled) : 0;
            if (win) {
                for (int j = 0; j < tl; j++) chosen[filled + j] = lane;
                key = 0ull;
            }
            filled += wsumi(tl);
        }
    }
    __syncthreads();

    // pipeline: wave wid owns slot wid
    const int tok = chosen[wid];
    float s = enc_t[tok * 64 + lane];
    float q = q_t[last_s * 64 + lane];
    const float cntf = (float)cnts[lane];

    #pragma unroll
    for (int p = 0; p < NP; p++) {
        sls[wid][lane] = s;                      // same-wave broadcast buffer
        float c0 = c_t[p * 64 + lane];
        const float4* mrow = (const float4*)(MT + p * 4096 + lane * 64);
        const float4* sp   = (const float4*)sls[wid];
        float a0 = 0.f, a1 = 0.f, a2 = 0.f, a3 = 0.f;
        #pragma unroll
        for (int i = 0; i < 16; i++) {
            float4 m4 = mrow[i];
            float4 s4v = sp[i];                  // uniform-address ds_read_b128
            a0 += s4v.x * m4.x; a1 += s4v.y * m4.y;
            a2 += s4v.z * m4.z; a3 += s4v.w * m4.w;
        }
        float lg = (c0 + ((a0 + a1) + (a2 + a3))) * 0.125f;

        float w = cntf * __expf(lg);             // no max-sub: |lg| ~ O(2); cnt=0 -> 0
        float denom = wsum(w);
        wls[wid][lane] = w;

        const float4* vrow = (const float4*)(SvT + p * 4096 + lane * 64);
        const float4* wp   = (const float4*)wls[wid];
        float b0 = 0.f, b1 = 0.f, b2 = 0.f, b3 = 0.f;
        #pragma unroll
        for (int i = 0; i < 16; i++) {
            float4 v4 = vrow[i];
            float4 w4 = wp[i];
            b0 += w4.x * v4.x; b1 += w4.y * v4.y;
            b2 += w4.z * v4.z; b3 += w4.w * v4.w;
        }
        float x = s + ((b0 + b1) + (b2 + b3)) / denom;

        float s1 = x, s2 = x * x;
        #pragma unroll
        for (int m = 1; m < 64; m <<= 1) { s1 += __shfl_xor(s1, m); s2 += __shfl_xor(s2, m); }
        float mu  = s1 * (1.f / 64.f);
        float var = s2 * (1.f / 64.f) - mu * mu;
        s = (x - mu) * rsqrtf(var + EPS) * rn_g[p * 64 + lane] + rn_b[p * 64 + lane];
    }

    float lk = wsum(s * q) * 0.125f;
    if (lane == 0) l4[wid] = lk;
    slN[wid][lane] = s;
    __syncthreads();

    if (wid == 0) {
        float e0 = __expf(l4[0]), e1 = __expf(l4[1]);
        float e2 = __expf(l4[2]), e3 = __expf(l4[3]);
        float dn = e0 + e1 + e2 + e3;
        float r = (e0 * slN[0][lane] + e1 * slN[1][lane]
                 + e2 * slN[2][lane] + e3 * slN[3][lane]) / dn;
        rbuf[lane] = r;
        const float4* orow = (const float4*)(owT + lane * 64);
        const float4* rp   = (const float4*)rbuf;
        float o0 = 0.f, o1 = 0.f, o2 = 0.f, o3 = 0.f;
        #pragma unroll
        for (int i = 0; i < 16; i++) {
            float4 ov = orow[i];
            float4 rv = rp[i];
            o0 += rv.x * ov.x; o1 += rv.y * ov.y;
            o2 += rv.z * ov.z; o3 += rv.w * ov.w;
        }
        out[(size_t)b * VOCAB + lane] = out_b[lane] + ((o0 + o1) + (o2 + o3));
    }
}

extern "C" void kernel_launch(void* const* d_in, const int* in_sizes, int n_in,
                              void* d_out, int out_size, void* d_ws, size_t ws_size,
                              hipStream_t stream) {
    const int*   seq    = (const int*)  d_in[0];
    const float* embed  = (const float*)d_in[1];
    const float* ff1_w  = (const float*)d_in[2];
    const float* ff1_b  = (const float*)d_in[3];
    const float* ff2_w  = (const float*)d_in[4];
    const float* ff2_b  = (const float*)d_in[5];
    const float* enc_g  = (const float*)d_in[6];
    const float* enc_b  = (const float*)d_in[7];
    const float* g1_w   = (const float*)d_in[8];
    const float* g1_b   = (const float*)d_in[9];
    const float* g2_w   = (const float*)d_in[10];
    const float* g2_b   = (const float*)d_in[11];
    const float* rq_w   = (const float*)d_in[12];
    const float* rq_b   = (const float*)d_in[13];
    const float* rk_w   = (const float*)d_in[14];
    const float* rk_b   = (const float*)d_in[15];
    const float* rv_w   = (const float*)d_in[16];
    const float* rv_b   = (const float*)d_in[17];
    const float* rn_g   = (const float*)d_in[18];
    const float* rn_b   = (const float*)d_in[19];
    const float* rd_q_w = (const float*)d_in[20];
    const float* rd_q_b = (const float*)d_in[21];
    const float* out_w  = (const float*)d_in[22];
    const float* out_b  = (const float*)d_in[23];
    float* out = (float*)d_out;

    const int B = in_sizes[0] / LSEQ;

    float* ws      = (float*)d_ws;
    float* enc_t   = ws;                // 4096
    float* score_t = ws + 4096;         // 64
    float* c_t     = ws + 4160;         // 192
    float* q_t     = ws + 4352;         // 4096
    float* MT      = ws + 8448;         // 12288
    float* SvT     = ws + 20736;        // 12288
    float* owT     = ws + 33024;        // 4096

    build_all<<<384, 64, 0, stream>>>(
        embed, ff1_w, ff1_b, ff2_w, ff2_b, enc_g, enc_b,
        g1_w, g1_b, g2_w, g2_b,
        rq_w, rq_b, rk_w, rk_b, rv_w, rv_b,
        rd_q_w, rd_q_b, out_w,
        enc_t, score_t, c_t, q_t, MT, SvT, owT);

    run_batches<<<B, 256, 0, stream>>>(
        seq, score_t, enc_t, c_t, q_t, MT, SvT, owT,
        rn_g, rn_b, out_b, out);
}

// Round 5
// 27.114 us; speedup vs baseline: 1.6328x; 1.1045x over previous
//
#include <hip/hip_runtime.h>
#include <math.h>

#define H 64
#define VOCAB 64
#define LSEQ 4096
#define NSLOTS 4
#define NP 3
#define EPS 1e-5f

typedef unsigned long long ull;

__device__ __forceinline__ float wsum(float x) {
    #pragma unroll
    for (int m = 1; m < 64; m <<= 1) x += __shfl_xor(x, m);
    return x;
}
__device__ __forceinline__ float wmax(float x) {
    #pragma unroll
    for (int m = 1; m < 64; m <<= 1) x = fmaxf(x, __shfl_xor(x, m));
    return x;
}

// ws layout (floats):
//   enc_t  [64][64]        @ 0      per-token encoder output
//   score  [64]            @ 4096   gate score per token
//   c_t    [3][64v]        @ 4160   rq_b . Sk[v]
//   q_t    [64][64]        @ 4352   read-head query per last-token
//   MT     [3][64v][64d]   @ 8448   (rq_w @ Sk^T)^T : logits_v = s . MT[v][:] + c[v]
//   SvT    [3][64h][64v]   @ 20736  Sv transposed: ao_h = w . SvT[h][:]
//   owT    [64v][64h]      @ 33024  out_w transposed

// ---- kernel 1: ALL tables in one launch. 384 blocks = 6 segs x 64 tokens. ----
__global__ __launch_bounds__(64) void build_all(
    const float* __restrict__ embed,
    const float* __restrict__ ff1_w, const float* __restrict__ ff1_b,
    const float* __restrict__ ff2_w, const float* __restrict__ ff2_b,
    const float* __restrict__ enc_g, const float* __restrict__ enc_b,
    const float* __restrict__ g1_w,  const float* __restrict__ g1_b,
    const float* __restrict__ g2_w,  const float* __restrict__ g2_b,
    const float* __restrict__ rq_w,  const float* __restrict__ rq_b,
    const float* __restrict__ rk_w,  const float* __restrict__ rk_b,
    const float* __restrict__ rv_w,  const float* __restrict__ rv_b,
    const float* __restrict__ rd_q_w, const float* __restrict__ rd_q_b,
    const float* __restrict__ out_w,
    float* __restrict__ enc_t, float* __restrict__ score_t,
    float* __restrict__ c_t, float* __restrict__ q_t,
    float* __restrict__ MT, float* __restrict__ SvT, float* __restrict__ owT)
{
    const int seg  = blockIdx.x >> 6;
    const int v    = blockIdx.x & 63;
    const int lane = threadIdx.x;

    __shared__ float h_s[H];
    __shared__ float a1[2 * H];
    __shared__ float hid_s[H];
    __shared__ float sk_s[H];

    h_s[lane] = embed[v * H + lane];
    __syncthreads();

    float pA[4] = {0, 0, 0, 0}, pB[4] = {0, 0, 0, 0};
    #pragma unroll
    for (int c4 = 0; c4 < 4; c4++)
        #pragma unroll
        for (int d = 0; d < 16; d++) {
            int dd = c4 * 16 + d;
            float hv = h_s[dd];
            pA[c4] += hv * ff1_w[dd * 128 + lane];
            pB[c4] += hv * ff1_w[dd * 128 + lane + 64];
        }
    a1[lane]      = fmaxf(ff1_b[lane]      + ((pA[0] + pA[1]) + (pA[2] + pA[3])), 0.f);
    a1[lane + 64] = fmaxf(ff1_b[lane + 64] + ((pB[0] + pB[1]) + (pB[2] + pB[3])), 0.f);
    __syncthreads();

    float pO[4] = {0, 0, 0, 0};
    #pragma unroll
    for (int c4 = 0; c4 < 4; c4++)
        #pragma unroll
        for (int j = 0; j < 32; j++) {
            int jj = c4 * 32 + j;
            pO[c4] += a1[jj] * ff2_w[jj * H + lane];
        }
    float o = ff2_b[lane] + ((pO[0] + pO[1]) + (pO[2] + pO[3]));

    float x = h_s[lane] + o;
    float s1 = x, s2 = x * x;
    #pragma unroll
    for (int m = 1; m < 64; m <<= 1) { s1 += __shfl_xor(s1, m); s2 += __shfl_xor(s2, m); }
    float mu  = s1 * (1.f / 64.f);
    float var = s2 * (1.f / 64.f) - mu * mu;
    float hid = (x - mu) * rsqrtf(var + EPS) * enc_g[lane] + enc_b[lane];
    hid_s[lane] = hid;
    __syncthreads();

    if (seg == 0) {
        enc_t[v * H + lane] = hid;
        float p = 0.f;
        if (lane < 32) {
            float a[2] = {0, 0};
            #pragma unroll
            for (int c2 = 0; c2 < 2; c2++)
                #pragma unroll
                for (int d = 0; d < 32; d++) {
                    int dd = c2 * 32 + d;
                    a[c2] += hid_s[dd] * g1_w[dd * 32 + lane];
                }
            p = fmaxf(g1_b[lane] + a[0] + a[1], 0.f) * g2_w[lane];
        }
        p = wsum(p);
        if (lane == 0) score_t[v] = 1.f / (1.f + expf(-(p + g2_b[0])));
        float qa[4] = {0, 0, 0, 0};
        #pragma unroll
        for (int c4 = 0; c4 < 4; c4++)
            #pragma unroll
            for (int d = 0; d < 16; d++) {
                int dd = c4 * 16 + d;
                qa[c4] += hid_s[dd] * rd_q_w[dd * H + lane];
            }
        q_t[v * H + lane] = rd_q_b[lane] + ((qa[0] + qa[1]) + (qa[2] + qa[3]));
    }

    if (seg < 3) {
        const int p = seg;
        float ka[4] = {0, 0, 0, 0};
        #pragma unroll
        for (int c4 = 0; c4 < 4; c4++)
            #pragma unroll
            for (int d = 0; d < 16; d++) {
                int dd = c4 * 16 + d;
                ka[c4] += hid_s[dd] * rk_w[(p * H + dd) * H + lane];
            }
        float skv = rk_b[p * H + lane] + ((ka[0] + ka[1]) + (ka[2] + ka[3]));
        sk_s[lane] = skv;
        float cpart = wsum(rq_b[p * H + lane] * skv);
        if (lane == 0) c_t[p * 64 + v] = cpart;
        __syncthreads();
        const float4* rw4 = (const float4*)(rq_w + (size_t)(p * 64 + lane) * 64);
        const float4* sk4 = (const float4*)sk_s;
        float ma[4] = {0, 0, 0, 0};
        #pragma unroll
        for (int i = 0; i < 16; i++) {
            float4 w4 = rw4[i];
            float4 s4 = sk4[i];
            ma[0] += w4.x * s4.x; ma[1] += w4.y * s4.y;
            ma[2] += w4.z * s4.z; ma[3] += w4.w * s4.w;
        }
        MT[p * 4096 + v * 64 + lane] = ((ma[0] + ma[1]) + (ma[2] + ma[3]));
    } else {
        const int p = seg - 3;
        float va[4] = {0, 0, 0, 0};
        #pragma unroll
        for (int c4 = 0; c4 < 4; c4++)
            #pragma unroll
            for (int d = 0; d < 16; d++) {
                int dd = c4 * 16 + d;
                va[c4] += hid_s[dd] * rv_w[(p * H + dd) * H + lane];
            }
        float svv = rv_b[p * H + lane] + ((va[0] + va[1]) + (va[2] + va[3]));
        SvT[p * 4096 + lane * 64 + v] = svv;
        if (seg == 3) owT[v * 64 + lane] = out_w[lane * 64 + v];
    }
}

// one re-encoding pass; MCUR preloaded; loads SvT[P] + (optionally) MT[P+1] at top
#define PASS(P, MCUR, MNXT, LOADNEXT)                                          \
{                                                                              \
    float4 vcur[16];                                                           \
    { const float4* b4 = (const float4*)(SvT + (P) * 4096 + lane * 64);        \
      _Pragma("unroll") for (int i = 0; i < 16; i++) vcur[i] = b4[i]; }        \
    if (LOADNEXT) {                                                            \
      const float4* b4 = (const float4*)(MT + ((P) + 1) * 4096 + lane * 64);   \
      _Pragma("unroll") for (int i = 0; i < 16; i++) MNXT[i] = b4[i]; }        \
    sls[wid][lane] = s;                                                        \
    const float4* sp = (const float4*)sls[wid];                                \
    float a0 = 0, a1 = 0, a2 = 0, a3 = 0;                                      \
    _Pragma("unroll") for (int i = 0; i < 16; i++) {                           \
        float4 s4v = sp[i];                                                    \
        a0 += s4v.x * MCUR[i].x; a1 += s4v.y * MCUR[i].y;                      \
        a2 += s4v.z * MCUR[i].z; a3 += s4v.w * MCUR[i].w; }                    \
    float lg = (cc[P] + ((a0 + a1) + (a2 + a3))) * 0.125f;                     \
    float w  = cntf * __expf(lg);                                              \
    float denom = wsum(w);                                                     \
    wls[wid][lane] = w;                                                        \
    const float4* wp = (const float4*)wls[wid];                                \
    float b0 = 0, b1 = 0, b2 = 0, b3 = 0;                                      \
    _Pragma("unroll") for (int i = 0; i < 16; i++) {                           \
        float4 w4 = wp[i];                                                     \
        b0 += w4.x * vcur[i].x; b1 += w4.y * vcur[i].y;                        \
        b2 += w4.z * vcur[i].z; b3 += w4.w * vcur[i].w; }                      \
    float x = s + ((b0 + b1) + (b2 + b3)) / denom;                             \
    float s1 = x, s2v = x * x;                                                 \
    _Pragma("unroll") for (int m = 1; m < 64; m <<= 1) {                       \
        s1 += __shfl_xor(s1, m); s2v += __shfl_xor(s2v, m); }                  \
    float mu  = s1 * (1.f / 64.f);                                             \
    float var = s2v * (1.f / 64.f) - mu * mu;                                  \
    s = (x - mu) * rsqrtf(var + EPS) * rg[P] + rb[P];                          \
}

// ---- kernel 2: per-batch histogram + selection + pipeline ----
__global__ __launch_bounds__(256) void run_batches(
    const int*   __restrict__ seq,
    const float* __restrict__ score_t, const float* __restrict__ enc_t,
    const float* __restrict__ c_t, const float* __restrict__ q_t,
    const float* __restrict__ MT, const float* __restrict__ SvT,
    const float* __restrict__ owT,
    const float* __restrict__ rn_g, const float* __restrict__ rn_b,
    const float* __restrict__ out_b,
    float* __restrict__ out)
{
    __shared__ int   whist[4][64];
    __shared__ int   last_sh;
    __shared__ float sls[NSLOTS][64];
    __shared__ float wls[NSLOTS][64];
    __shared__ float slN[NSLOTS][64];
    __shared__ float l4[NSLOTS];
    __shared__ float rbuf[64];

    const int b = blockIdx.x, tid = threadIdx.x;
    const int wid = tid >> 6, lane = tid & 63;

    // early prefetches (all independent of seq/selection)
    float sc = score_t[lane];
    float cc[NP], rg[NP], rb[NP];
    #pragma unroll
    for (int p = 0; p < NP; p++) {
        cc[p] = c_t[p * 64 + lane];
        rg[p] = rn_g[p * 64 + lane];
        rb[p] = rn_b[p * 64 + lane];
    }
    float4 mA[16], mB[16];
    {   // MT pass-0 rows: in flight during seq load + histogram
        const float4* b4 = (const float4*)(MT + lane * 64);
        #pragma unroll
        for (int i = 0; i < 16; i++) mA[i] = b4[i];
    }

    const int4* s4 = (const int4*)(seq + (size_t)b * LSEQ);
    int4 t0 = s4[tid];
    int4 t1 = s4[tid + 256];
    int4 t2 = s4[tid + 512];
    int4 t3 = s4[tid + 768];
    if (tid == 255) last_sh = t3.w;

    whist[wid][lane] = 0;            // wave-private bank: no barrier needed
    {
        int* hw = whist[wid];
        atomicAdd(&hw[t0.x], 1); atomicAdd(&hw[t0.y], 1);
        atomicAdd(&hw[t0.z], 1); atomicAdd(&hw[t0.w], 1);
        atomicAdd(&hw[t1.x], 1); atomicAdd(&hw[t1.y], 1);
        atomicAdd(&hw[t1.z], 1); atomicAdd(&hw[t1.w], 1);
        atomicAdd(&hw[t2.x], 1); atomicAdd(&hw[t2.y], 1);
        atomicAdd(&hw[t2.z], 1); atomicAdd(&hw[t2.w], 1);
        atomicAdd(&hw[t3.x], 1); atomicAdd(&hw[t3.y], 1);
        atomicAdd(&hw[t3.z], 1); atomicAdd(&hw[t3.w], 1);
    }
    __syncthreads();

    const int cnt = whist[0][lane] + whist[1][lane] + whist[2][lane] + whist[3][lane];
    const float cntf = (float)cnt;

    // selection, redundant in every wave: greedy by (score desc, token asc), fill by counts
    int my_tok = 0;
    {
        float key = cnt > 0 ? sc : -1.f;
        int filled = 0;
        bool have = false;
        #pragma unroll 1
        for (int r = 0; r < NSLOTS && filled < NSLOTS; r++) {
            float m = wmax(key);
            ull win = __ballot(key == m);
            int tk = __ffsll(win) - 1;
            int c  = __shfl(cnt, tk);
            if (!have && (unsigned)(wid - filled) < (unsigned)c) { my_tok = tk; have = true; }
            filled += c;
            if (lane == tk) key = -1.f;
        }
    }

    float s = enc_t[my_tok * 64 + lane];
    float q = q_t[last_sh * 64 + lane];

    PASS(0, mA, mB, 1)
    PASS(1, mB, mA, 1)
    PASS(2, mA, mB, 0)

    float lk = wsum(s * q) * 0.125f;
    if (lane == 0) l4[wid] = lk;
    slN[wid][lane] = s;

    // wave 0: issue owT + out_b loads before the barrier (independent of r)
    float4 ow[16];
    float ob = 0.f;
    if (wid == 0) {
        const float4* b4 = (const float4*)(owT + lane * 64);
        #pragma unroll
        for (int i = 0; i < 16; i++) ow[i] = b4[i];
        ob = out_b[lane];
    }
    __syncthreads();

    if (wid == 0) {
        float e0 = __expf(l4[0]), e1 = __expf(l4[1]);
        float e2 = __expf(l4[2]), e3 = __expf(l4[3]);
        float dn = e0 + e1 + e2 + e3;
        float r = (e0 * slN[0][lane] + e1 * slN[1][lane]
                 + e2 * slN[2][lane] + e3 * slN[3][lane]) / dn;
        rbuf[lane] = r;
        const float4* rp = (const float4*)rbuf;
        float o0 = 0, o1 = 0, o2 = 0, o3 = 0;
        #pragma unroll
        for (int i = 0; i < 16; i++) {
            float4 rv = rp[i];
            o0 += rv.x * ow[i].x; o1 += rv.y * ow[i].y;
            o2 += rv.z * ow[i].z; o3 += rv.w * ow[i].w;
        }
        out[(size_t)b * VOCAB + lane] = ob + ((o0 + o1) + (o2 + o3));
    }
}

extern "C" void kernel_launch(void* const* d_in, const int* in_sizes, int n_in,
                              void* d_out, int out_size, void* d_ws, size_t ws_size,
                              hipStream_t stream) {
    const int*   seq    = (const int*)  d_in[0];
    const float* embed  = (const float*)d_in[1];
    const float* ff1_w  = (const float*)d_in[2];
    const float* ff1_b  = (const float*)d_in[3];
    const float* ff2_w  = (const float*)d_in[4];
    const float* ff2_b  = (const float*)d_in[5];
    const float* enc_g  = (const float*)d_in[6];
    const float* enc_b  = (const float*)d_in[7];
    const float* g1_w   = (const float*)d_in[8];
    const float* g1_b   = (const float*)d_in[9];
    const float* g2_w   = (const float*)d_in[10];
    const float* g2_b   = (const float*)d_in[11];
    const float* rq_w   = (const float*)d_in[12];
    const float* rq_b   = (const float*)d_in[13];
    const float* rk_w   = (const float*)d_in[14];
    const float* rk_b   = (const float*)d_in[15];
    const float* rv_w   = (const float*)d_in[16];
    const float* rv_b   = (const float*)d_in[17];
    const float* rn_g   = (const float*)d_in[18];
    const float* rn_b   = (const float*)d_in[19];
    const float* rd_q_w = (const float*)d_in[20];
    const float* rd_q_b = (const float*)d_in[21];
    const float* out_w  = (const float*)d_in[22];
    const float* out_b  = (const float*)d_in[23];
    float* out = (float*)d_out;

    const int B = in_sizes[0] / LSEQ;

    float* ws      = (float*)d_ws;
    float* enc_t   = ws;                // 4096
    float* score_t = ws + 4096;         // 64
    float* c_t     = ws + 4160;         // 192
    float* q_t     = ws + 4352;         // 4096
    float* MT      = ws + 8448;         // 12288
    float* SvT     = ws + 20736;        // 12288
    float* owT     = ws + 33024;        // 4096

    build_all<<<384, 64, 0, stream>>>(
        embed, ff1_w, ff1_b, ff2_w, ff2_b, enc_g, enc_b,
        g1_w, g1_b, g2_w, g2_b,
        rq_w, rq_b, rk_w, rk_b, rv_w, rv_b,
        rd_q_w, rd_q_b, out_w,
        enc_t, score_t, c_t, q_t, MT, SvT, owT);

    run_batches<<<B, 256, 0, stream>>>(
        seq, score_t, enc_t, c_t, q_t, MT, SvT, owT,
        rn_g, rn_b, out_b, out);
}